// Round 7
// baseline (589.218 us; speedup 1.0000x reference)
//
#include <hip/hip_runtime.h>
#include <hip/hip_cooperative_groups.h>

namespace cg = cooperative_groups;

#define B_ 8
#define T_ 4096
#define E_ 1024
#define K_ 128

typedef __bf16 bf16;
typedef bf16 bf16x8 __attribute__((ext_vector_type(8)));
typedef bf16 bf16x4 __attribute__((ext_vector_type(4)));
typedef float f32x4 __attribute__((ext_vector_type(4)));

// ================= Single fused cooperative kernel (256 blocks) =================
__global__ __launch_bounds__(256, 2) void fused_all(
    const float* __restrict__ x, const float* __restrict__ mu,
    const float* __restrict__ kp, const float* __restrict__ bp,
    bf16* __restrict__ xb, bf16* __restrict__ xbT,
    float* __restrict__ att, bf16* __restrict__ attp,
    bf16* __restrict__ selbT, bf16* __restrict__ mub,
    float* __restrict__ out)
{
    cg::grid_group grid = cg::this_grid();
    const int gb = blockIdx.x;            // 0..255
    const int tid = threadIdx.x;
    const int w = tid >> 6, lane = tid & 63, g = lane >> 4, ln = lane & 15;

    __shared__ __align__(16) char smraw[33792];   // union across phases

    // ---------------- Phase 0: mu -> bf16 (131072 elems, 2/thread) ----------------
    {
        const int i0 = gb * 256 + tid;
        mub[i0] = (bf16)mu[i0];
        mub[i0 + 65536] = (bf16)mu[i0 + 65536];
    }
    grid.sync();

    // ---------------- Phase A: xb, xbT, att (512 tiles, 2/block) ----------------
    for (int it = gb; it < 512; it += 256) {
        const int b = it >> 6;
        const int tile = it & 63;
        bf16 (*xs)[256] = (bf16(*)[256])smraw;  // (t,e) at xs[t][e ^ ((t&7)<<3)]
        const int t0 = tile * 64;
        const int tr = tid >> 4, es = tid & 15;
        f32x4 acc[8];
#pragma unroll
        for (int m = 0; m < 8; ++m) acc[m] = (f32x4){0.f, 0.f, 0.f, 0.f};

        for (int ph = 0; ph < 4; ++ph) {
            const int ep = ph * 256;
#pragma unroll
            for (int r = 0; r < 4; ++r) {
                const int t = r * 16 + tr;
                const float* src = x + ((size_t)(b * T_ + t0 + t)) * E_ + ep;
                bf16* dst = xb + ((size_t)(b * T_ + t0 + t)) * E_ + ep;
#pragma unroll
                for (int q = 0; q < 4; ++q) {
                    const int el = es * 4 + q * 64;
                    f32x4 v = *(const f32x4*)(src + el);
                    bf16x4 o;
                    o[0] = (bf16)v[0]; o[1] = (bf16)v[1];
                    o[2] = (bf16)v[2]; o[3] = (bf16)v[3];
                    *(bf16x4*)(dst + el) = o;
                    *(bf16x4*)&xs[t][el ^ ((t & 7) << 3)] = o;
                }
            }
            __syncthreads();
            const int tt = w * 16 + ln;
#pragma unroll
            for (int s = 0; s < 8; ++s) {
                bf16x8 bfr = *(const bf16x8*)&xs[tt][(s * 32 + g * 8) ^ ((tt & 7) << 3)];
                const int ecol = ep + s * 32 + g * 8;
#pragma unroll
                for (int m = 0; m < 8; ++m) {
                    bf16x8 af = *(const bf16x8*)(mub + (size_t)(m * 16 + ln) * E_ + ecol);
                    acc[m] = __builtin_amdgcn_mfma_f32_16x16x32_bf16(af, bfr, acc[m], 0, 0, 0);
                }
            }
            const int e4 = tid >> 2, ts = tid & 3;
#pragma unroll
            for (int p = 0; p < 4; ++p) {
                const int el = p * 64 + e4;
                bf16* dst2 = xbT + ((size_t)b * E_ + ep + el) * T_ + t0 + ts * 16;
#pragma unroll
                for (int u = 0; u < 2; ++u) {
                    bf16x8 o;
#pragma unroll
                    for (int j = 0; j < 8; ++j) {
                        const int t = ts * 16 + u * 8 + j;
                        o[j] = xs[t][el ^ ((t & 7) << 3)];
                    }
                    *(bf16x8*)(dst2 + u * 8) = o;
                }
            }
            __syncthreads();
        }
#pragma unroll
        for (int m = 0; m < 8; ++m)
#pragma unroll
            for (int r = 0; r < 4; ++r)
                att[((size_t)b * K_ + m * 16 + g * 4 + r) * T_ + t0 + w * 16 + ln] =
                    acc[m][r] * 0.03125f;
    }
    grid.sync();

    // ---------------- Phase B: softmax (1024 rows, 4/block) ----------------
    {
        float* red = (float*)smraw;
        for (int rep = 0; rep < 4; ++rep) {
            const int row = gb * 4 + rep;
            const f32x4* p = (const f32x4*)(att + (size_t)row * T_);
            f32x4 v[4];
            float m = -1e30f;
#pragma unroll
            for (int i = 0; i < 4; ++i) {
                v[i] = p[i * 256 + tid];
                m = fmaxf(m, fmaxf(fmaxf(v[i][0], v[i][1]), fmaxf(v[i][2], v[i][3])));
            }
#pragma unroll
            for (int off = 32; off > 0; off >>= 1) m = fmaxf(m, __shfl_xor(m, off));
            if (lane == 0) red[w] = m;
            __syncthreads();
            m = fmaxf(fmaxf(red[0], red[1]), fmaxf(red[2], red[3]));
            float s = 0.f;
#pragma unroll
            for (int i = 0; i < 4; ++i) {
                v[i][0] = __expf(v[i][0] - m);
                v[i][1] = __expf(v[i][1] - m);
                v[i][2] = __expf(v[i][2] - m);
                v[i][3] = __expf(v[i][3] - m);
                s += v[i][0] + v[i][1] + v[i][2] + v[i][3];
            }
#pragma unroll
            for (int off = 32; off > 0; off >>= 1) s += __shfl_xor(s, off);
            if (lane == 0) red[4 + w] = s;
            __syncthreads();
            const float inv = 1.f / (red[4] + red[5] + red[6] + red[7]);
            bf16x4* outp = (bf16x4*)(attp + (size_t)row * T_);
#pragma unroll
            for (int i = 0; i < 4; ++i) {
                bf16x4 o;
                o[0] = (bf16)(v[i][0] * inv);
                o[1] = (bf16)(v[i][1] * inv);
                o[2] = (bf16)(v[i][2] * inv);
                o[3] = (bf16)(v[i][3] * inv);
                outp[i * 256 + tid] = o;
            }
            __syncthreads();
        }
    }
    grid.sync();

    // ---------------- Phase C: selbT (512 tiles, 2/block) ----------------
    for (int it = gb; it < 512; it += 256) {
        const int b = it >> 6;
        const int e0 = (it & 63) * 16;
        float (*part)[16][132] = (float(*)[16][132])smraw;
        f32x4 acc[8];
#pragma unroll
        for (int m = 0; m < 8; ++m) acc[m] = (f32x4){0.f, 0.f, 0.f, 0.f};
        const bf16* xrow = xbT + ((size_t)b * E_ + e0 + ln) * T_ + w * 1024 + g * 8;
        const bf16* abase = attp + (size_t)b * K_ * T_ + w * 1024 + g * 8;
#pragma unroll 2
        for (int tc = 0; tc < 1024; tc += 32) {
            bf16x8 af = *(const bf16x8*)(xrow + tc);
#pragma unroll
            for (int m = 0; m < 8; ++m) {
                bf16x8 bfr = *(const bf16x8*)(abase + (size_t)(m * 16 + ln) * T_ + tc);
                acc[m] = __builtin_amdgcn_mfma_f32_16x16x32_bf16(af, bfr, acc[m], 0, 0, 0);
            }
        }
#pragma unroll
        for (int m = 0; m < 8; ++m)
#pragma unroll
            for (int r = 0; r < 4; ++r)
                part[w][g * 4 + r][m * 16 + ln] = acc[m][r];
        __syncthreads();
        const int e = tid >> 4, ks = tid & 15;
        bf16x8 o;
#pragma unroll
        for (int i = 0; i < 8; ++i) {
            const int kq = ks * 8 + i;
            o[i] = (bf16)(part[0][e][kq] + part[1][e][kq] + part[2][e][kq] + part[3][e][kq]);
        }
        *(bf16x8*)(selbT + ((size_t)b * E_ + e0 + e) * K_ + ks * 8) = o;
        __syncthreads();
    }
    grid.sync();

    // ---------------- Phase D: out (512 tiles, 2/block) ----------------
    {
        const float kk = kp[0], bb = bp[0];
        for (int it = gb; it < 512; it += 256) {
            const int b = it >> 6;
            const int t0d = (it & 63) * 64;
            bf16 (*pT)[128] = (bf16(*)[128])smraw;   // (t,k) at pT[t][k ^ ((t&7)<<3)]
            const int u = tid & 3;
#pragma unroll
            for (int p = 0; p < 2; ++p) {
                const int k = p * 64 + (tid >> 2);
                const bf16* src = attp + ((size_t)b * K_ + k) * T_ + t0d + u * 16;
#pragma unroll
                for (int h = 0; h < 2; ++h) {
                    bf16x8 v = *(const bf16x8*)(src + h * 8);
#pragma unroll
                    for (int j = 0; j < 8; ++j) {
                        const int t = u * 16 + h * 8 + j;
                        pT[t][k ^ ((t & 7) << 3)] = v[j];
                    }
                }
            }
            __syncthreads();
            for (int et = 0; et < 16; ++et) {
                const int e0d = et * 64 + w * 16;
                f32x4 acc[4];
#pragma unroll
                for (int m = 0; m < 4; ++m) acc[m] = (f32x4){0.f, 0.f, 0.f, 0.f};
#pragma unroll
                for (int ks = 0; ks < 4; ++ks) {
                    const int k0 = ks * 32 + g * 8;
                    bf16x8 bfr = *(const bf16x8*)(selbT + ((size_t)b * E_ + e0d + ln) * K_ + k0);
#pragma unroll
                    for (int m = 0; m < 4; ++m) {
                        const int t = m * 16 + ln;
                        bf16x8 af = *(const bf16x8*)&pT[t][k0 ^ ((t & 7) << 3)];
                        acc[m] = __builtin_amdgcn_mfma_f32_16x16x32_bf16(af, bfr, acc[m], 0, 0, 0);
                    }
                }
#pragma unroll
                for (int m = 0; m < 4; ++m) {
#pragma unroll
                    for (int r = 0; r < 4; ++r) {
                        const int t = t0d + m * 16 + g * 4 + r;
                        const size_t idx = ((size_t)b * T_ + t) * E_ + e0d + ln;
                        out[idx] = kk * ((float)xb[idx] + acc[m][r]) + bb;
                    }
                }
            }
            __syncthreads();
        }
    }
}

// ================= Fallback pipeline (round-5 proven kernels) =================
__global__ __launch_bounds__(256) void k0_cvt_mu(const float* __restrict__ mu,
                                                 bf16* __restrict__ mub) {
    int i = blockIdx.x * 256 + threadIdx.x;
    mub[i] = (bf16)mu[i];
}

__global__ __launch_bounds__(256) void ka_cvt_att(const float* __restrict__ x,
                                                  const bf16* __restrict__ mub,
                                                  bf16* __restrict__ xb,
                                                  bf16* __restrict__ xbT,
                                                  float* __restrict__ att) {
    const int b = blockIdx.y;
    const int t0 = blockIdx.x * 64;
    const int tid = threadIdx.x;
    const int w = tid >> 6, lane = tid & 63, g = lane >> 4, ln = lane & 15;
    const int tr = tid >> 4, es = tid & 15;
    __shared__ bf16 xs[64][256];

    f32x4 acc[8];
#pragma unroll
    for (int m = 0; m < 8; ++m) acc[m] = (f32x4){0.f, 0.f, 0.f, 0.f};

    for (int ph = 0; ph < 4; ++ph) {
        const int ep = ph * 256;
#pragma unroll
        for (int r = 0; r < 4; ++r) {
            const int t = r * 16 + tr;
            const float* src = x + ((size_t)(b * T_ + t0 + t)) * E_ + ep;
            bf16* dst = xb + ((size_t)(b * T_ + t0 + t)) * E_ + ep;
#pragma unroll
            for (int q = 0; q < 4; ++q) {
                const int el = es * 4 + q * 64;
                f32x4 v = *(const f32x4*)(src + el);
                bf16x4 o;
                o[0] = (bf16)v[0]; o[1] = (bf16)v[1];
                o[2] = (bf16)v[2]; o[3] = (bf16)v[3];
                *(bf16x4*)(dst + el) = o;
                *(bf16x4*)&xs[t][el ^ ((t & 7) << 3)] = o;
            }
        }
        __syncthreads();
        const int tt = w * 16 + ln;
#pragma unroll
        for (int s = 0; s < 8; ++s) {
            bf16x8 bfr = *(const bf16x8*)&xs[tt][(s * 32 + g * 8) ^ ((tt & 7) << 3)];
            const int ecol = ep + s * 32 + g * 8;
#pragma unroll
            for (int m = 0; m < 8; ++m) {
                bf16x8 af = *(const bf16x8*)(mub + (size_t)(m * 16 + ln) * E_ + ecol);
                acc[m] = __builtin_amdgcn_mfma_f32_16x16x32_bf16(af, bfr, acc[m], 0, 0, 0);
            }
        }
        const int e4 = tid >> 2, ts = tid & 3;
#pragma unroll
        for (int p = 0; p < 4; ++p) {
            const int el = p * 64 + e4;
            bf16* dst2 = xbT + ((size_t)b * E_ + ep + el) * T_ + t0 + ts * 16;
#pragma unroll
            for (int u = 0; u < 2; ++u) {
                bf16x8 o;
#pragma unroll
                for (int j = 0; j < 8; ++j) {
                    const int t = ts * 16 + u * 8 + j;
                    o[j] = xs[t][el ^ ((t & 7) << 3)];
                }
                *(bf16x8*)(dst2 + u * 8) = o;
            }
        }
        __syncthreads();
    }
#pragma unroll
    for (int m = 0; m < 8; ++m)
#pragma unroll
        for (int r = 0; r < 4; ++r)
            att[((size_t)b * K_ + m * 16 + g * 4 + r) * T_ + t0 + w * 16 + ln] =
                acc[m][r] * 0.03125f;
}

__global__ __launch_bounds__(256) void k2_softmax(const float* __restrict__ att,
                                                  bf16* __restrict__ attp) {
    const int row = blockIdx.x;
    const int tid = threadIdx.x;
    const f32x4* p = (const f32x4*)(att + (size_t)row * T_);
    f32x4 v[4];
    float m = -1e30f;
#pragma unroll
    for (int i = 0; i < 4; ++i) {
        v[i] = p[i * 256 + tid];
        m = fmaxf(m, fmaxf(fmaxf(v[i][0], v[i][1]), fmaxf(v[i][2], v[i][3])));
    }
#pragma unroll
    for (int off = 32; off > 0; off >>= 1) m = fmaxf(m, __shfl_xor(m, off));
    __shared__ float redm[4], reds[4];
    const int wave = tid >> 6, lane = tid & 63;
    if (lane == 0) redm[wave] = m;
    __syncthreads();
    m = fmaxf(fmaxf(redm[0], redm[1]), fmaxf(redm[2], redm[3]));
    float s = 0.f;
#pragma unroll
    for (int i = 0; i < 4; ++i) {
        v[i][0] = __expf(v[i][0] - m);
        v[i][1] = __expf(v[i][1] - m);
        v[i][2] = __expf(v[i][2] - m);
        v[i][3] = __expf(v[i][3] - m);
        s += v[i][0] + v[i][1] + v[i][2] + v[i][3];
    }
#pragma unroll
    for (int off = 32; off > 0; off >>= 1) s += __shfl_xor(s, off);
    if (lane == 0) reds[wave] = s;
    __syncthreads();
    const float inv = 1.f / (reds[0] + reds[1] + reds[2] + reds[3]);
    bf16x4* outp = (bf16x4*)(attp + (size_t)row * T_);
#pragma unroll
    for (int i = 0; i < 4; ++i) {
        bf16x4 o;
        o[0] = (bf16)(v[i][0] * inv);
        o[1] = (bf16)(v[i][1] * inv);
        o[2] = (bf16)(v[i][2] * inv);
        o[3] = (bf16)(v[i][3] * inv);
        outp[i * 256 + tid] = o;
    }
}

__global__ __launch_bounds__(256) void kc_sel(const bf16* __restrict__ xbT,
                                              const bf16* __restrict__ attp,
                                              bf16* __restrict__ selbT) {
    const int eblk = blockIdx.x;
    const int b = blockIdx.y;
    const int tid = threadIdx.x;
    const int w = tid >> 6, lane = tid & 63, g = lane >> 4, ln = lane & 15;
    const int e0 = eblk * 16;

    f32x4 acc[8];
#pragma unroll
    for (int m = 0; m < 8; ++m) acc[m] = (f32x4){0.f, 0.f, 0.f, 0.f};

    const bf16* xrow = xbT + ((size_t)b * E_ + e0 + ln) * T_ + w * 1024 + g * 8;
    const bf16* abase = attp + (size_t)b * K_ * T_ + w * 1024 + g * 8;
#pragma unroll 2
    for (int t0 = 0; t0 < 1024; t0 += 32) {
        bf16x8 af = *(const bf16x8*)(xrow + t0);
#pragma unroll
        for (int m = 0; m < 8; ++m) {
            bf16x8 bfr = *(const bf16x8*)(abase + (size_t)(m * 16 + ln) * T_ + t0);
            acc[m] = __builtin_amdgcn_mfma_f32_16x16x32_bf16(af, bfr, acc[m], 0, 0, 0);
        }
    }
    __shared__ float part[4][16][132];
#pragma unroll
    for (int m = 0; m < 8; ++m)
#pragma unroll
        for (int r = 0; r < 4; ++r)
            part[w][g * 4 + r][m * 16 + ln] = acc[m][r];
    __syncthreads();
    const int e = tid >> 4, ks = tid & 15;
    bf16x8 o;
#pragma unroll
    for (int i = 0; i < 8; ++i) {
        const int kq = ks * 8 + i;
        o[i] = (bf16)(part[0][e][kq] + part[1][e][kq] + part[2][e][kq] + part[3][e][kq]);
    }
    *(bf16x8*)(selbT + ((size_t)b * E_ + e0 + e) * K_ + ks * 8) = o;
}

__global__ __launch_bounds__(256) void k5_out(const bf16* __restrict__ xb,
                                              const bf16* __restrict__ attp,
                                              const bf16* __restrict__ selbT,
                                              const float* __restrict__ kp,
                                              const float* __restrict__ bp,
                                              float* __restrict__ out) {
    const int b = blockIdx.z;
    const int t0 = blockIdx.x * 128;
    const int tid = threadIdx.x;
    const int w = tid >> 6, lane = tid & 63, g = lane >> 4, ln = lane & 15;
    const int e0 = blockIdx.y * 64 + w * 16;
    const float kk = kp[0], bb = bp[0];
    __shared__ bf16 pT[128][128];

    const int u = tid & 7;
#pragma unroll
    for (int p = 0; p < 4; ++p) {
        const int k = p * 32 + (tid >> 3);
        const bf16* src = attp + ((size_t)b * K_ + k) * T_ + t0 + u * 16;
#pragma unroll
        for (int h = 0; h < 2; ++h) {
            bf16x8 v = *(const bf16x8*)(src + h * 8);
#pragma unroll
            for (int j = 0; j < 8; ++j) {
                const int t = u * 16 + h * 8 + j;
                pT[t][k ^ (j << 3)] = v[j];
            }
        }
    }
    __syncthreads();

    f32x4 acc[8];
#pragma unroll
    for (int m = 0; m < 8; ++m) acc[m] = (f32x4){0.f, 0.f, 0.f, 0.f};

#pragma unroll
    for (int ks = 0; ks < 4; ++ks) {
        const int k0 = ks * 32 + g * 8;
        bf16x8 bfr = *(const bf16x8*)(selbT + ((size_t)b * E_ + e0 + ln) * K_ + k0);
#pragma unroll
        for (int m = 0; m < 8; ++m) {
            const int t = m * 16 + ln;
            bf16x8 af = *(const bf16x8*)&pT[t][k0 ^ ((t & 7) << 3)];
            acc[m] = __builtin_amdgcn_mfma_f32_16x16x32_bf16(af, bfr, acc[m], 0, 0, 0);
        }
    }
#pragma unroll
    for (int m = 0; m < 8; ++m) {
#pragma unroll
        for (int r = 0; r < 4; ++r) {
            const int t = t0 + m * 16 + g * 4 + r;
            const size_t idx = ((size_t)b * T_ + t) * E_ + e0 + ln;
            out[idx] = kk * ((float)xb[idx] + acc[m][r]) + bb;
        }
    }
}

extern "C" void kernel_launch(void* const* d_in, const int* in_sizes, int n_in,
                              void* d_out, int out_size, void* d_ws, size_t ws_size,
                              hipStream_t stream) {
    const float* x  = (const float*)d_in[0];
    const float* mu = (const float*)d_in[1];
    // d_in[2]=bias, d_in[3]=Wr, d_in[4]=Wl are dead code in the reference forward.
    const float* kp = (const float*)d_in[5];
    const float* bp = (const float*)d_in[6];
    float* out = (float*)d_out;

    char* ws = (char*)d_ws;
    bf16*  xb    = (bf16*)(ws);                    //  67,108,864
    bf16*  xbT   = (bf16*)(ws + 67108864);         //  67,108,864
    float* att   = (float*)(ws + 134217728);       //  16,777,216
    bf16*  attp  = (bf16*)(ws + 150994944);        //   8,388,608
    bf16*  selbT = (bf16*)(ws + 159383552);        //   2,097,152
    bf16*  mub   = (bf16*)(ws + 161480704);        //     262,144  (~154 MB)

    void* args[] = {(void*)&x, (void*)&mu, (void*)&kp, (void*)&bp,
                    (void*)&xb, (void*)&xbT, (void*)&att, (void*)&attp,
                    (void*)&selbT, (void*)&mub, (void*)&out};
    hipError_t err = hipLaunchCooperativeKernel(reinterpret_cast<void*>(fused_all),
                                                dim3(256), dim3(256), args, 0, stream);
    if (err != hipSuccess) {
        (void)hipGetLastError();   // clear sticky error, run proven fallback
        k0_cvt_mu<<<dim3(512), 256, 0, stream>>>(mu, mub);
        ka_cvt_att<<<dim3(64, 8), 256, 0, stream>>>(x, mub, xb, xbT, att);
        k2_softmax<<<dim3(1024), 256, 0, stream>>>(att, attp);
        kc_sel<<<dim3(64, 8), 256, 0, stream>>>(xbT, attp, selbT);
        k5_out<<<dim3(32, 16, 8), 256, 0, stream>>>(xb, attp, selbT, kp, bp, out);
    }
}

// Round 8
// 244.035 us; speedup vs baseline: 2.4145x; 2.4145x over previous
//
#include <hip/hip_runtime.h>

#define B_ 8
#define T_ 4096
#define E_ 1024
#define K_ 128

typedef __bf16 bf16;
typedef bf16 bf16x8 __attribute__((ext_vector_type(8)));
typedef bf16 bf16x4 __attribute__((ext_vector_type(4)));
typedef float f32x4 __attribute__((ext_vector_type(4)));

// ---------------- K0: convert mu to bf16 ----------------
__global__ __launch_bounds__(256) void k0_cvt_mu(const float* __restrict__ mu,
                                                 bf16* __restrict__ mub) {
    int i = blockIdx.x * 256 + threadIdx.x;
    mub[i] = (bf16)mu[i];
}

// ---------------- K1: attP[h,b,k,t] = sum_{e in half h} mu[k,e]*x[b,t,e] ----------------
// grid (T/64, 2, B) = 1024 blocks, 256 thr (4 waves). Wave: 16 t x 128 k.
// Load burst per e-step: 2 x-loads + 8 mu-loads issued before the 8 MFMAs.
// VGPR budget ~90 -> 4-5 waves/SIMD resident.
__global__ __launch_bounds__(256) void k1_att(const float* __restrict__ x,
                                              const bf16* __restrict__ mub,
                                              float* __restrict__ attP) {
    const int b = blockIdx.z;
    const int h = blockIdx.y;
    const int w = threadIdx.x >> 6, lane = threadIdx.x & 63;
    const int g = lane >> 4, ln = lane & 15;
    const int t = blockIdx.x * 64 + w * 16 + ln;

    f32x4 acc[8];
#pragma unroll
    for (int m = 0; m < 8; ++m) acc[m] = (f32x4){0.f, 0.f, 0.f, 0.f};

    const float* xrow = x + ((size_t)b * T_ + t) * E_ + h * 512 + g * 8;
    const bf16* mu0 = mub + h * 512 + g * 8;
#pragma unroll 2
    for (int e0 = 0; e0 < 512; e0 += 32) {
        f32x4 u0 = *(const f32x4*)(xrow + e0);
        f32x4 u1 = *(const f32x4*)(xrow + e0 + 4);
        bf16x8 af[8];
#pragma unroll
        for (int m = 0; m < 8; ++m)
            af[m] = *(const bf16x8*)(mu0 + (size_t)(m * 16 + ln) * E_ + e0);
        bf16x8 bf;
        bf[0] = (bf16)u0[0]; bf[1] = (bf16)u0[1]; bf[2] = (bf16)u0[2]; bf[3] = (bf16)u0[3];
        bf[4] = (bf16)u1[0]; bf[5] = (bf16)u1[1]; bf[6] = (bf16)u1[2]; bf[7] = (bf16)u1[3];
#pragma unroll
        for (int m = 0; m < 8; ++m)
            acc[m] = __builtin_amdgcn_mfma_f32_16x16x32_bf16(af[m], bf, acc[m], 0, 0, 0);
    }
#pragma unroll
    for (int m = 0; m < 8; ++m)
#pragma unroll
        for (int r = 0; r < 4; ++r)
            attP[(((size_t)h * B_ + b) * K_ + m * 16 + g * 4 + r) * T_ + t] = acc[m][r];
}

// ---------------- K2: fused half-sum + softmax -> attp bf16 (1024 blocks) ----------------
__global__ __launch_bounds__(256) void k2_softmax(const float* __restrict__ attP,
                                                  bf16* __restrict__ attp) {
    const int row = blockIdx.x;   // b*K + k
    const int tid = threadIdx.x;
    const f32x4* p0 = (const f32x4*)(attP + (size_t)row * T_);
    const f32x4* p1 = (const f32x4*)(attP + ((size_t)(B_ * K_) + row) * T_);
    f32x4 v[4];
    float m = -1e30f;
#pragma unroll
    for (int i = 0; i < 4; ++i) {
        f32x4 a = p0[i * 256 + tid];
        f32x4 c = p1[i * 256 + tid];
        v[i] = (a + c) * 0.03125f;
        m = fmaxf(m, fmaxf(fmaxf(v[i][0], v[i][1]), fmaxf(v[i][2], v[i][3])));
    }
#pragma unroll
    for (int off = 32; off > 0; off >>= 1) m = fmaxf(m, __shfl_xor(m, off));
    __shared__ float redm[4], reds[4];
    const int wave = tid >> 6, lane = tid & 63;
    if (lane == 0) redm[wave] = m;
    __syncthreads();
    m = fmaxf(fmaxf(redm[0], redm[1]), fmaxf(redm[2], redm[3]));
    float s = 0.f;
#pragma unroll
    for (int i = 0; i < 4; ++i) {
        v[i][0] = __expf(v[i][0] - m);
        v[i][1] = __expf(v[i][1] - m);
        v[i][2] = __expf(v[i][2] - m);
        v[i][3] = __expf(v[i][3] - m);
        s += v[i][0] + v[i][1] + v[i][2] + v[i][3];
    }
#pragma unroll
    for (int off = 32; off > 0; off >>= 1) s += __shfl_xor(s, off);
    if (lane == 0) reds[wave] = s;
    __syncthreads();
    const float inv = 1.f / (reds[0] + reds[1] + reds[2] + reds[3]);
    bf16x4* outp = (bf16x4*)(attp + (size_t)row * T_);
#pragma unroll
    for (int i = 0; i < 4; ++i) {
        bf16x4 o;
        o[0] = (bf16)(v[i][0] * inv);
        o[1] = (bf16)(v[i][1] * inv);
        o[2] = (bf16)(v[i][2] * inv);
        o[3] = (bf16)(v[i][3] * inv);
        outp[i * 256 + tid] = o;
    }
}

// ---------------- K4: selpT[c,b,e,k] = sum_{t in chunk c} attp[b,k,t]*x[b,t,e] ----------------
// grid (E/64, 8 chunks, B) = 1024 blocks, 256 thr (4 waves). Wave: 16 e x 128 k.
// Load burst per t-step: 8 scalar fp32 x + 8 attp rows, then 8 MFMAs.
// Epilogue: LDS transpose -> coalesced k-fastest stores.
__global__ __launch_bounds__(256) void k4_sel(const float* __restrict__ x,
                                              const bf16* __restrict__ attp,
                                              float* __restrict__ selpT) {
    const int eblk = blockIdx.x;
    const int chunk = blockIdx.y;
    const int b = blockIdx.z;
    const int tid = threadIdx.x;
    const int w = tid >> 6, lane = tid & 63, g = lane >> 4, ln = lane & 15;
    const int e0 = eblk * 64;
    const int e = e0 + w * 16 + ln;

    f32x4 acc[8];
#pragma unroll
    for (int m = 0; m < 8; ++m) acc[m] = (f32x4){0.f, 0.f, 0.f, 0.f};

    const int tb = chunk * 512;
#pragma unroll 2
    for (int t0 = 0; t0 < 512; t0 += 32) {
        const int t = tb + t0 + g * 8;
        float xv[8];
#pragma unroll
        for (int j = 0; j < 8; ++j)
            xv[j] = x[((size_t)b * T_ + t + j) * E_ + e];
        bf16x8 af[8];
#pragma unroll
        for (int m = 0; m < 8; ++m)
            af[m] = *(const bf16x8*)(attp + ((size_t)b * K_ + m * 16 + ln) * T_ + t);
        bf16x8 bf;
#pragma unroll
        for (int j = 0; j < 8; ++j) bf[j] = (bf16)xv[j];
#pragma unroll
        for (int m = 0; m < 8; ++m)
            acc[m] = __builtin_amdgcn_mfma_f32_16x16x32_bf16(af[m], bf, acc[m], 0, 0, 0);
    }
    __shared__ float tl[64][132];
#pragma unroll
    for (int m = 0; m < 8; ++m)
#pragma unroll
        for (int r = 0; r < 4; ++r)
            tl[w * 16 + ln][m * 16 + g * 4 + r] = acc[m][r];
    __syncthreads();
    float* dst = selpT + ((size_t)chunk * B_ + b) * E_ * K_ + (size_t)e0 * K_;
#pragma unroll
    for (int rr = 0; rr < 8; ++rr) {
        const int slot = rr * 256 + tid;
        const int ee = slot >> 5;
        const int kq = slot & 31;
        *(f32x4*)(dst + (size_t)ee * K_ + kq * 4) = *(f32x4*)&tl[ee][kq * 4];
    }
}

// ---------------- K4b: flat reduce over 8 chunks -> selbT bf16 [b][e][k] (1024 blocks) ----
__global__ __launch_bounds__(256) void k4b_reduce(const float* __restrict__ selpT,
                                                  bf16* __restrict__ selbT) {
    const size_t gid = (size_t)blockIdx.x * 256 + threadIdx.x;  // 262144 f32x4 slots
    const size_t f = gid * 4;
    f32x4 s = (f32x4){0.f, 0.f, 0.f, 0.f};
#pragma unroll
    for (int c = 0; c < 8; ++c)
        s += *(const f32x4*)(selpT + (size_t)c * (B_ * E_ * K_) + f);
    bf16x4 o;
    o[0] = (bf16)s[0]; o[1] = (bf16)s[1]; o[2] = (bf16)s[2]; o[3] = (bf16)s[3];
    *(bf16x4*)(selbT + f) = o;
}

// ---------------- K5: out = k*(x + attp^T @ selbT) + b  (attp transposed in LDS) ----------
// grid (T/128, E/64, B) = 4096 blocks, 256 thr (4 waves). Wave: 128 t x 16 e.
__global__ __launch_bounds__(256) void k5_out(const float* __restrict__ x,
                                              const bf16* __restrict__ attp,
                                              const bf16* __restrict__ selbT,
                                              const float* __restrict__ kp,
                                              const float* __restrict__ bp,
                                              float* __restrict__ out) {
    const int b = blockIdx.z;
    const int t0 = blockIdx.x * 128;
    const int tid = threadIdx.x;
    const int w = tid >> 6, lane = tid & 63, g = lane >> 4, ln = lane & 15;
    const int e0 = blockIdx.y * 64 + w * 16;
    const float kk = kp[0], bb = bp[0];
    __shared__ bf16 pT[128][128];   // (t,k) at pT[t][k ^ ((t&7)<<3)]

    // stage attp[b][*][t0..+128] transposed (16 x 16B burst loads)
    const int u = tid & 7;
#pragma unroll
    for (int p = 0; p < 4; ++p) {
        const int k = p * 32 + (tid >> 3);
        const bf16* src = attp + ((size_t)b * K_ + k) * T_ + t0 + u * 16;
#pragma unroll
        for (int hh = 0; hh < 2; ++hh) {
            bf16x8 v = *(const bf16x8*)(src + hh * 8);
#pragma unroll
            for (int j = 0; j < 8; ++j) {
                const int t = u * 16 + hh * 8 + j;   // t&7 == j
                pT[t][k ^ (j << 3)] = v[j];
            }
        }
    }
    __syncthreads();

    f32x4 acc[8];
#pragma unroll
    for (int m = 0; m < 8; ++m) acc[m] = (f32x4){0.f, 0.f, 0.f, 0.f};

#pragma unroll
    for (int ks = 0; ks < 4; ++ks) {
        const int k0 = ks * 32 + g * 8;
        bf16x8 bfr = *(const bf16x8*)(selbT + ((size_t)b * E_ + e0 + ln) * K_ + k0);
#pragma unroll
        for (int m = 0; m < 8; ++m) {
            const int t = m * 16 + ln;
            bf16x8 af = *(const bf16x8*)&pT[t][k0 ^ ((t & 7) << 3)];
            acc[m] = __builtin_amdgcn_mfma_f32_16x16x32_bf16(af, bfr, acc[m], 0, 0, 0);
        }
    }
#pragma unroll
    for (int m = 0; m < 8; ++m) {
#pragma unroll
        for (int r = 0; r < 4; ++r) {
            const int t = t0 + m * 16 + g * 4 + r;
            const size_t idx = ((size_t)b * T_ + t) * E_ + e0 + ln;
            out[idx] = kk * (x[idx] + acc[m][r]) + bb;
        }
    }
}

extern "C" void kernel_launch(void* const* d_in, const int* in_sizes, int n_in,
                              void* d_out, int out_size, void* d_ws, size_t ws_size,
                              hipStream_t stream) {
    const float* x  = (const float*)d_in[0];
    const float* mu = (const float*)d_in[1];
    // d_in[2]=bias, d_in[3]=Wr, d_in[4]=Wl are dead code in the reference forward.
    const float* kp = (const float*)d_in[5];
    const float* bp = (const float*)d_in[6];
    float* out = (float*)d_out;

    char* ws = (char*)d_ws;
    // Region A (33,554,432 B): attP [2][B][K][T] (K1->K2), then reused as
    // selpT [8][B][E][K] (K4->K4b). Stream-ordered, no overlap hazard.
    float* attP  = (float*)(ws);
    float* selpT = (float*)(ws);
    bf16*  attp  = (bf16*)(ws + 33554432);   //  8,388,608
    bf16*  selbT = (bf16*)(ws + 41943040);   //  2,097,152
    bf16*  mub   = (bf16*)(ws + 44040192);   //    262,144  (total ~44.3 MB)

    k0_cvt_mu<<<dim3(512), 256, 0, stream>>>(mu, mub);
    k1_att<<<dim3(64, 2, 8), 256, 0, stream>>>(x, mub, attP);
    k2_softmax<<<dim3(1024), 256, 0, stream>>>(attP, attp);
    k4_sel<<<dim3(16, 8, 8), 256, 0, stream>>>(x, attp, selpT);
    k4b_reduce<<<dim3(1024), 256, 0, stream>>>(selpT, selbT);
    k5_out<<<dim3(32, 16, 8), 256, 0, stream>>>(x, attp, selbT, kp, bp, out);
}

// Round 9
// 236.694 us; speedup vs baseline: 2.4894x; 1.0310x over previous
//
#include <hip/hip_runtime.h>

#define B_ 8
#define T_ 4096
#define E_ 1024
#define K_ 128

typedef __bf16 bf16;
typedef bf16 bf16x8 __attribute__((ext_vector_type(8)));
typedef bf16 bf16x4 __attribute__((ext_vector_type(4)));
typedef float f32x4 __attribute__((ext_vector_type(4)));

// ---------------- K0: convert mu to bf16 ----------------
__global__ __launch_bounds__(256) void k0_cvt_mu(const float* __restrict__ mu,
                                                 bf16* __restrict__ mub) {
    int i = blockIdx.x * 256 + threadIdx.x;
    mub[i] = (bf16)mu[i];
}

// ---------------- K1: attP[h,b,k,t] = sum_{e in half h} mu[k,e]*x[b,t,e]; also xb=(bf16)x ----
// grid (T/64, 2, B) = 1024 blocks, 256 thr (4 waves). Wave: 16 t x 128 k.
// Per e-step burst: 2 x-loads + 8 mu-loads before 8 MFMAs; xb store is 64B/row-coalesced.
__global__ __launch_bounds__(256) void k1_att(const float* __restrict__ x,
                                              const bf16* __restrict__ mub,
                                              float* __restrict__ attP,
                                              bf16* __restrict__ xb) {
    const int b = blockIdx.z;
    const int h = blockIdx.y;
    const int w = threadIdx.x >> 6, lane = threadIdx.x & 63;
    const int g = lane >> 4, ln = lane & 15;
    const int t = blockIdx.x * 64 + w * 16 + ln;

    f32x4 acc[8];
#pragma unroll
    for (int m = 0; m < 8; ++m) acc[m] = (f32x4){0.f, 0.f, 0.f, 0.f};

    const float* xrow = x + ((size_t)b * T_ + t) * E_ + h * 512 + g * 8;
    bf16* xbrow = xb + ((size_t)b * T_ + t) * E_ + h * 512 + g * 8;
    const bf16* mu0 = mub + h * 512 + g * 8;
#pragma unroll 2
    for (int e0 = 0; e0 < 512; e0 += 32) {
        f32x4 u0 = *(const f32x4*)(xrow + e0);
        f32x4 u1 = *(const f32x4*)(xrow + e0 + 4);
        bf16x8 af[8];
#pragma unroll
        for (int m = 0; m < 8; ++m)
            af[m] = *(const bf16x8*)(mu0 + (size_t)(m * 16 + ln) * E_ + e0);
        bf16x8 bf;
        bf[0] = (bf16)u0[0]; bf[1] = (bf16)u0[1]; bf[2] = (bf16)u0[2]; bf[3] = (bf16)u0[3];
        bf[4] = (bf16)u1[0]; bf[5] = (bf16)u1[1]; bf[6] = (bf16)u1[2]; bf[7] = (bf16)u1[3];
        *(bf16x8*)(xbrow + e0) = bf;
#pragma unroll
        for (int m = 0; m < 8; ++m)
            acc[m] = __builtin_amdgcn_mfma_f32_16x16x32_bf16(af[m], bf, acc[m], 0, 0, 0);
    }
#pragma unroll
    for (int m = 0; m < 8; ++m)
#pragma unroll
        for (int r = 0; r < 4; ++r)
            attP[(((size_t)h * B_ + b) * K_ + m * 16 + g * 4 + r) * T_ + t] = acc[m][r];
}

// ---------------- K2: fused half-sum + softmax -> attp bf16 (1024 blocks) ----------------
__global__ __launch_bounds__(256) void k2_softmax(const float* __restrict__ attP,
                                                  bf16* __restrict__ attp) {
    const int row = blockIdx.x;   // b*K + k
    const int tid = threadIdx.x;
    const f32x4* p0 = (const f32x4*)(attP + (size_t)row * T_);
    const f32x4* p1 = (const f32x4*)(attP + ((size_t)(B_ * K_) + row) * T_);
    f32x4 v[4];
    float m = -1e30f;
#pragma unroll
    for (int i = 0; i < 4; ++i) {
        f32x4 a = p0[i * 256 + tid];
        f32x4 c = p1[i * 256 + tid];
        v[i] = (a + c) * 0.03125f;
        m = fmaxf(m, fmaxf(fmaxf(v[i][0], v[i][1]), fmaxf(v[i][2], v[i][3])));
    }
#pragma unroll
    for (int off = 32; off > 0; off >>= 1) m = fmaxf(m, __shfl_xor(m, off));
    __shared__ float redm[4], reds[4];
    const int wave = tid >> 6, lane = tid & 63;
    if (lane == 0) redm[wave] = m;
    __syncthreads();
    m = fmaxf(fmaxf(redm[0], redm[1]), fmaxf(redm[2], redm[3]));
    float s = 0.f;
#pragma unroll
    for (int i = 0; i < 4; ++i) {
        v[i][0] = __expf(v[i][0] - m);
        v[i][1] = __expf(v[i][1] - m);
        v[i][2] = __expf(v[i][2] - m);
        v[i][3] = __expf(v[i][3] - m);
        s += v[i][0] + v[i][1] + v[i][2] + v[i][3];
    }
#pragma unroll
    for (int off = 32; off > 0; off >>= 1) s += __shfl_xor(s, off);
    if (lane == 0) reds[wave] = s;
    __syncthreads();
    const float inv = 1.f / (reds[0] + reds[1] + reds[2] + reds[3]);
    bf16x4* outp = (bf16x4*)(attp + (size_t)row * T_);
#pragma unroll
    for (int i = 0; i < 4; ++i) {
        bf16x4 o;
        o[0] = (bf16)(v[i][0] * inv);
        o[1] = (bf16)(v[i][1] * inv);
        o[2] = (bf16)(v[i][2] * inv);
        o[3] = (bf16)(v[i][3] * inv);
        outp[i * 256 + tid] = o;
    }
}

// ---------------- K4: selpT[c,b,e,k](bf16) = sum_{t in chunk c} attp[b,k,t]*xb[b,t,e] ------
// grid (E/64, 8 chunks, B) = 1024 blocks, 256 thr (4 waves). Wave: 16 e x 128 k.
__global__ __launch_bounds__(256) void k4_sel(const bf16* __restrict__ xb,
                                              const bf16* __restrict__ attp,
                                              bf16* __restrict__ selpT) {
    const int eblk = blockIdx.x;
    const int chunk = blockIdx.y;
    const int b = blockIdx.z;
    const int tid = threadIdx.x;
    const int w = tid >> 6, lane = tid & 63, g = lane >> 4, ln = lane & 15;
    const int e0 = eblk * 64;
    const int e = e0 + w * 16 + ln;

    f32x4 acc[8];
#pragma unroll
    for (int m = 0; m < 8; ++m) acc[m] = (f32x4){0.f, 0.f, 0.f, 0.f};

    const int tb = chunk * 512;
#pragma unroll 2
    for (int t0 = 0; t0 < 512; t0 += 32) {
        const int t = tb + t0 + g * 8;
        bf16 xv[8];
#pragma unroll
        for (int j = 0; j < 8; ++j)
            xv[j] = xb[((size_t)b * T_ + t + j) * E_ + e];
        bf16x8 af[8];
#pragma unroll
        for (int m = 0; m < 8; ++m)
            af[m] = *(const bf16x8*)(attp + ((size_t)b * K_ + m * 16 + ln) * T_ + t);
        bf16x8 bf;
#pragma unroll
        for (int j = 0; j < 8; ++j) bf[j] = xv[j];
#pragma unroll
        for (int m = 0; m < 8; ++m)
            acc[m] = __builtin_amdgcn_mfma_f32_16x16x32_bf16(af[m], bf, acc[m], 0, 0, 0);
    }
    __shared__ float tl[64][132];
#pragma unroll
    for (int m = 0; m < 8; ++m)
#pragma unroll
        for (int r = 0; r < 4; ++r)
            tl[w * 16 + ln][m * 16 + g * 4 + r] = acc[m][r];
    __syncthreads();
    bf16* dst = selpT + ((size_t)chunk * B_ + b) * E_ * K_ + (size_t)e0 * K_;
#pragma unroll
    for (int rr = 0; rr < 4; ++rr) {
        const int slot = rr * 256 + tid;
        const int ee = slot >> 4;
        const int kq = slot & 15;     // 8 bf16 per slot
        bf16x8 o;
#pragma unroll
        for (int j = 0; j < 8; ++j) o[j] = (bf16)tl[ee][kq * 8 + j];
        *(bf16x8*)(dst + (size_t)ee * K_ + kq * 8) = o;
    }
}

// ---------------- K4b: flat reduce over 8 chunks -> selbT bf16 [b][e][k] (512 blocks) ----
__global__ __launch_bounds__(256) void k4b_reduce(const bf16* __restrict__ selpT,
                                                  bf16* __restrict__ selbT) {
    const size_t gid = (size_t)blockIdx.x * 256 + threadIdx.x;  // 131072 bf16x8 slots
    const size_t f = gid * 8;
    float s[8];
#pragma unroll
    for (int j = 0; j < 8; ++j) s[j] = 0.f;
#pragma unroll
    for (int c = 0; c < 8; ++c) {
        bf16x8 v = *(const bf16x8*)(selpT + (size_t)c * (B_ * E_ * K_) + f);
#pragma unroll
        for (int j = 0; j < 8; ++j) s[j] += (float)v[j];
    }
    bf16x8 o;
#pragma unroll
    for (int j = 0; j < 8; ++j) o[j] = (bf16)s[j];
    *(bf16x8*)(selbT + f) = o;
}

// ---------------- K5: out = k*(xb + attp^T @ selbT) + b  (attp transposed in LDS) ----------
// grid (T/64, E/64, B) = 8192 blocks, 256 thr (4 waves). Wave: 64 t x 16 e, acc[4].
__global__ __launch_bounds__(256) void k5_out(const bf16* __restrict__ xb,
                                              const bf16* __restrict__ attp,
                                              const bf16* __restrict__ selbT,
                                              const float* __restrict__ kp,
                                              const float* __restrict__ bp,
                                              float* __restrict__ out) {
    const int b = blockIdx.z;
    const int t0 = blockIdx.x * 64;
    const int tid = threadIdx.x;
    const int w = tid >> 6, lane = tid & 63, g = lane >> 4, ln = lane & 15;
    const int e0 = blockIdx.y * 64 + w * 16;
    const float kk = kp[0], bb = bp[0];
    __shared__ bf16 pT[64][128];   // (t,k) at pT[t][k ^ ((t&7)<<3)]

    // stage attp[b][*][t0..+64] transposed: thread (u=tid&3, kr=tid>>2) loads 2x bf16x8
    const int u = tid & 3;
    const int kr = tid >> 2;       // 0..63
#pragma unroll
    for (int p = 0; p < 2; ++p) {
        const int k = p * 64 + kr;
        const bf16* src = attp + ((size_t)b * K_ + k) * T_ + t0 + u * 16;
#pragma unroll
        for (int hh = 0; hh < 2; ++hh) {
            bf16x8 v = *(const bf16x8*)(src + hh * 8);
#pragma unroll
            for (int j = 0; j < 8; ++j) {
                const int t = u * 16 + hh * 8 + j;   // t&7 == j
                pT[t][k ^ (j << 3)] = v[j];
            }
        }
    }
    __syncthreads();

    f32x4 acc[4];
#pragma unroll
    for (int m = 0; m < 4; ++m) acc[m] = (f32x4){0.f, 0.f, 0.f, 0.f};

#pragma unroll
    for (int ks = 0; ks < 4; ++ks) {
        const int k0 = ks * 32 + g * 8;
        bf16x8 bfr = *(const bf16x8*)(selbT + ((size_t)b * E_ + e0 + ln) * K_ + k0);
#pragma unroll
        for (int m = 0; m < 4; ++m) {
            const int t = m * 16 + ln;
            bf16x8 af = *(const bf16x8*)&pT[t][k0 ^ ((t & 7) << 3)];
            acc[m] = __builtin_amdgcn_mfma_f32_16x16x32_bf16(af, bfr, acc[m], 0, 0, 0);
        }
    }
#pragma unroll
    for (int m = 0; m < 4; ++m) {
#pragma unroll
        for (int r = 0; r < 4; ++r) {
            const int t = t0 + m * 16 + g * 4 + r;
            const size_t idx = ((size_t)b * T_ + t) * E_ + e0 + ln;
            out[idx] = kk * ((float)xb[idx] + acc[m][r]) + bb;
        }
    }
}

extern "C" void kernel_launch(void* const* d_in, const int* in_sizes, int n_in,
                              void* d_out, int out_size, void* d_ws, size_t ws_size,
                              hipStream_t stream) {
    const float* x  = (const float*)d_in[0];
    const float* mu = (const float*)d_in[1];
    // d_in[2]=bias, d_in[3]=Wr, d_in[4]=Wl are dead code in the reference forward.
    const float* kp = (const float*)d_in[5];
    const float* bp = (const float*)d_in[6];
    float* out = (float*)d_out;

    char* ws = (char*)d_ws;
    // Region A (33,554,432 B): attP [2][B][K][T] f32 (K1->K2), then reused as
    // selpT [8][B][E][K] bf16 (K4->K4b). Stream-ordered, no overlap hazard.
    float* attP  = (float*)(ws);
    bf16*  selpT = (bf16*)(ws);
    bf16*  attp  = (bf16*)(ws + 33554432);   //  8,388,608
    bf16*  selbT = (bf16*)(ws + 41943040);   //  2,097,152
    bf16*  mub   = (bf16*)(ws + 44040192);   //    262,144
    bf16*  xb    = (bf16*)(ws + 44302336);   // 67,108,864  (total ~111 MB)

    k0_cvt_mu<<<dim3(512), 256, 0, stream>>>(mu, mub);
    k1_att<<<dim3(64, 2, 8), 256, 0, stream>>>(x, mub, attP, xb);
    k2_softmax<<<dim3(1024), 256, 0, stream>>>(attP, attp);
    k4_sel<<<dim3(16, 8, 8), 256, 0, stream>>>(xb, attp, selpT);
    k4b_reduce<<<dim3(512), 256, 0, stream>>>(selpT, selbT);
    k5_out<<<dim3(64, 16, 8), 256, 0, stream>>>(xb, attp, selbT, kp, bp, out);
}